// Round 1
// baseline (12686.357 us; speedup 1.0000x reference)
//
#include <hip/hip_runtime.h>
#include <math.h>

#define B_   64
#define L_   680
#define C_   1024
#define BLC_ ((size_t)B_ * (size_t)L_ * (size_t)C_)

// ---------------------------------------------------------------------------
// Generic fp32 GEMM: C[M,N] = scale * (A[M,K] @ B[K,N] + bias)
// scale = sigmoid(*gate) if gate != nullptr else 1.
// Requires M%64==0, N%64==0, K%16==0 (true for all call sites).
// 64x64 tile, BK=16, 256 threads, 4x4 micro-tile per thread.
// ---------------------------------------------------------------------------
#define TILE 64
#define BK 16

__global__ __launch_bounds__(256)
void gemm_kernel(const float* __restrict__ A, const float* __restrict__ Bm,
                 float* __restrict__ Cm, int M, int N, int K,
                 const float* __restrict__ bias, const float* __restrict__ gate)
{
    __shared__ float As[BK][TILE + 4];   // stored transposed: As[k][m], pad->16B-aligned rows
    __shared__ float Bs[BK][TILE + 4];   // Bs[k][n]
    const int t  = threadIdx.x;
    const int tx = t & 15, ty = t >> 4;
    const int bm = blockIdx.y * TILE, bn = blockIdx.x * TILE;
    // loaders: A tile 64x16 -> one float4 along k per thread; B tile 16x64 -> one float4 along n
    const int am = t >> 2, akq = (t & 3) * 4;
    const int bkr = t >> 4, bcq = (t & 15) * 4;

    float acc[4][4] = {};

    for (int k0 = 0; k0 < K; k0 += BK) {
        float4 av = *(const float4*)&A[(size_t)(bm + am) * (size_t)K + (size_t)(k0 + akq)];
        float4 bv = *(const float4*)&Bm[(size_t)(k0 + bkr) * (size_t)N + (size_t)(bn + bcq)];
        __syncthreads();
        As[akq + 0][am] = av.x;
        As[akq + 1][am] = av.y;
        As[akq + 2][am] = av.z;
        As[akq + 3][am] = av.w;
        *(float4*)&Bs[bkr][bcq] = bv;
        __syncthreads();
        #pragma unroll
        for (int k = 0; k < BK; ++k) {
            float4 a4 = *(const float4*)&As[k][ty * 4];
            float4 b4 = *(const float4*)&Bs[k][tx * 4];
            acc[0][0] += a4.x * b4.x; acc[0][1] += a4.x * b4.y; acc[0][2] += a4.x * b4.z; acc[0][3] += a4.x * b4.w;
            acc[1][0] += a4.y * b4.x; acc[1][1] += a4.y * b4.y; acc[1][2] += a4.y * b4.z; acc[1][3] += a4.y * b4.w;
            acc[2][0] += a4.z * b4.x; acc[2][1] += a4.z * b4.y; acc[2][2] += a4.z * b4.z; acc[2][3] += a4.z * b4.w;
            acc[3][0] += a4.w * b4.x; acc[3][1] += a4.w * b4.y; acc[3][2] += a4.w * b4.z; acc[3][3] += a4.w * b4.w;
        }
    }

    float scale = 1.0f;
    if (gate) scale = 1.0f / (1.0f + __expf(-gate[0]));
    float4 bias4 = make_float4(0.f, 0.f, 0.f, 0.f);
    if (bias) bias4 = *(const float4*)&bias[bn + tx * 4];

    #pragma unroll
    for (int r = 0; r < 4; ++r) {
        size_t row = (size_t)(bm + ty * 4 + r);
        float4 o;
        o.x = scale * (acc[r][0] + bias4.x);
        o.y = scale * (acc[r][1] + bias4.y);
        o.z = scale * (acc[r][2] + bias4.z);
        o.w = scale * (acc[r][3] + bias4.w);
        *(float4*)&Cm[row * (size_t)N + (size_t)(bn + tx * 4)] = o;
    }
}

// ---------------------------------------------------------------------------
// Fused segmented attention with online softmax (fp32).
// Block = (batch b, 16-row tile of a segment). Key chunks of 256, c chunks of 32.
// Each thread owns 4 output columns (c0 = t*4) for all 16 rows (64 fp32 accs).
// ---------------------------------------------------------------------------
#define NB 256
#define CC 32

__global__ __launch_bounds__(256)
void attn_kernel(const float* __restrict__ Q, const float* __restrict__ Kk,
                 const float* __restrict__ Vv, const float* __restrict__ lt,
                 float* __restrict__ O)
{
    __shared__ float Qc[16][CC + 1];        // 2.1 KB
    __shared__ float Kc[NB][CC + 1];        // 33 KB
    __shared__ float Ss[16][NB + 1];        // 16.4 KB
    __shared__ float m_s[16], l_s[16], al_s[16];

    // hardcoded begin_ends / tiling for PATCH_NUMS (1,2,3,4,5,6,8,10,13,16)
    const int seg_start_tab[10] = {0, 1, 5, 14, 30, 55, 91, 155, 255, 424};
    const int seg_len_tab[10]   = {1, 4, 9, 16, 25, 36, 64, 100, 169, 256};
    const int tile_pfx[11]      = {0, 1, 2, 3, 4, 6, 9, 13, 20, 31, 47};

    const int t = threadIdx.x;
    const int b = blockIdx.y;
    int tb = blockIdx.x;
    int seg = 0;
    while (tb >= tile_pfx[seg + 1]) seg++;
    const int r0     = (tb - tile_pfx[seg]) * 16;
    const int sstart = seg_start_tab[seg];
    const int slen   = seg_len_tab[seg];
    const int nk     = 128 * (seg + 1);

    float tempv = __expf(lt[0]);
    tempv = fminf(fmaxf(tempv, 0.05f), 1.0f);
    const float sc = (1.0f / 32.0f) / tempv;   // inv_scale / temp

    const int tn = t & 63;     // key sub-index for score phase
    const int tr = t >> 6;     // row group (wave id)
    const int c0 = t * 4;      // owned output columns

    if (t < 16) { m_s[t] = -1e30f; l_s[t] = 0.f; }
    float oa[16][4] = {};

    for (int n0 = 0; n0 < nk; n0 += NB) {
        const int kn = min(NB, nk - n0);

        // ---- Phase A: scores S[16][kn] = Q_tile @ K_chunk^T ----
        float sacc[4][4] = {};
        for (int cc0 = 0; cc0 < C_; cc0 += CC) {
            __syncthreads();
            if (t < 128) {
                int r = t >> 3, cq = (t & 7) * 4;
                int gr = r0 + r; if (gr >= slen) gr = 0;   // clamp pad rows (discarded later)
                float4 qv = *(const float4*)&Q[((size_t)b * L_ + (size_t)(sstart + gr)) * C_ + (size_t)(cc0 + cq)];
                Qc[r][cq + 0] = qv.x; Qc[r][cq + 1] = qv.y; Qc[r][cq + 2] = qv.z; Qc[r][cq + 3] = qv.w;
            }
            #pragma unroll
            for (int j = 0; j < 8; ++j) {
                int idx = j * 256 + t;
                int r = idx >> 3, cq = (idx & 7) * 4;
                if (r < kn) {
                    float4 kv = *(const float4*)&Kk[(size_t)(n0 + r) * C_ + (size_t)(cc0 + cq)];
                    Kc[r][cq + 0] = kv.x; Kc[r][cq + 1] = kv.y; Kc[r][cq + 2] = kv.z; Kc[r][cq + 3] = kv.w;
                }
            }
            __syncthreads();
            #pragma unroll
            for (int c = 0; c < CC; ++c) {
                float a0 = Qc[tr * 4 + 0][c];
                float a1 = Qc[tr * 4 + 1][c];
                float a2 = Qc[tr * 4 + 2][c];
                float a3 = Qc[tr * 4 + 3][c];
                float b0 = Kc[tn][c];
                float b1 = Kc[tn + 64][c];
                float b2 = Kc[tn + 128][c];
                float b3 = Kc[tn + 192][c];
                sacc[0][0] += a0 * b0; sacc[0][1] += a0 * b1; sacc[0][2] += a0 * b2; sacc[0][3] += a0 * b3;
                sacc[1][0] += a1 * b0; sacc[1][1] += a1 * b1; sacc[1][2] += a1 * b2; sacc[1][3] += a1 * b3;
                sacc[2][0] += a2 * b0; sacc[2][1] += a2 * b1; sacc[2][2] += a2 * b2; sacc[2][3] += a2 * b3;
                sacc[3][0] += a3 * b0; sacc[3][1] += a3 * b1; sacc[3][2] += a3 * b2; sacc[3][3] += a3 * b3;
            }
        }
        #pragma unroll
        for (int ri = 0; ri < 4; ++ri) {
            #pragma unroll
            for (int j = 0; j < 4; ++j) {
                int n = tn + 64 * j;
                if (n < kn) Ss[tr * 4 + ri][n] = sacc[ri][j] * sc;
            }
        }
        __syncthreads();

        // ---- Phase B: online softmax update (wave w handles rows 4w..4w+3) ----
        {
            const int lane = t & 63;
            const int w = t >> 6;
            for (int rr = 0; rr < 4; ++rr) {
                const int r = w * 4 + rr;
                float mx = -1e30f;
                for (int n = lane; n < kn; n += 64) mx = fmaxf(mx, Ss[r][n]);
                #pragma unroll
                for (int off = 32; off > 0; off >>= 1) mx = fmaxf(mx, __shfl_down(mx, off));
                mx = __shfl(mx, 0);
                float mo = m_s[r];
                float mn = fmaxf(mo, mx);
                float sum = 0.f;
                for (int n = lane; n < kn; n += 64) {
                    float p = __expf(Ss[r][n] - mn);
                    Ss[r][n] = p;
                    sum += p;
                }
                #pragma unroll
                for (int off = 32; off > 0; off >>= 1) sum += __shfl_down(sum, off);
                if (lane == 0) {
                    float al = __expf(mo - mn);
                    al_s[r] = al;
                    m_s[r]  = mn;
                    l_s[r]  = al * l_s[r] + sum;
                }
            }
        }
        __syncthreads();

        // ---- Phase C: rescale + O += P @ V_chunk ----
        #pragma unroll
        for (int r = 0; r < 16; ++r) {
            float al = al_s[r];
            oa[r][0] *= al; oa[r][1] *= al; oa[r][2] *= al; oa[r][3] *= al;
        }
        for (int n = 0; n < kn; ++n) {
            float4 v4 = *(const float4*)&Vv[(size_t)(n0 + n) * C_ + (size_t)c0];
            #pragma unroll
            for (int r = 0; r < 16; ++r) {
                float p = Ss[r][n];
                oa[r][0] += p * v4.x; oa[r][1] += p * v4.y; oa[r][2] += p * v4.z; oa[r][3] += p * v4.w;
            }
        }
    }
    __syncthreads();

    const int rows_valid = min(16, slen - r0);
    #pragma unroll
    for (int r = 0; r < 16; ++r) {
        if (r < rows_valid) {
            float inv = 1.0f / l_s[r];
            float4 o;
            o.x = oa[r][0] * inv; o.y = oa[r][1] * inv; o.z = oa[r][2] * inv; o.w = oa[r][3] * inv;
            *(float4*)&O[((size_t)b * L_ + (size_t)(sstart + r0 + r)) * C_ + (size_t)c0] = o;
        }
    }
}

__global__ void tail_kernel(float* p) { p[0] = 0.f; p[1] = 0.f; }

// ---------------------------------------------------------------------------
extern "C" void kernel_launch(void* const* d_in, const int* in_sizes, int n_in,
                              void* d_out, int out_size, void* d_ws, size_t ws_size,
                              hipStream_t stream) {
    const float* x   = (const float*)d_in[0];
    const float* mem = (const float*)d_in[1];
    const float* Wq  = (const float*)d_in[2];
    const float* Wk  = (const float*)d_in[3];
    const float* Wv  = (const float*)d_in[4];
    const float* wk1 = (const float*)d_in[5];
    const float* bk1 = (const float*)d_in[6];
    const float* wk2 = (const float*)d_in[7];
    const float* bk2 = (const float*)d_in[8];
    const float* wv1 = (const float*)d_in[9];
    const float* bv1 = (const float*)d_in[10];
    const float* wv2 = (const float*)d_in[11];
    const float* bv2 = (const float*)d_in[12];
    const float* gk  = (const float*)d_in[13];
    const float* gv  = (const float*)d_in[14];
    const float* lt  = (const float*)d_in[15];
    // d_in[16] = begin_ends (deterministic, hardcoded in attn_kernel)

    float* out = (float*)d_out;
    float* ws  = (float*)d_ws;

    // workspace layout (floats): keys[1280*1024], vals[1280*1024], hk[43520*64], hv[43520*64]
    float* keys = ws;
    float* vals = keys + 1310720;
    float* hk   = vals + 1310720;
    float* hv   = hk + 2785280;

    float* qbuf = out;                 // scratch: query lives in out[0 : BLC)
    float* mc   = out + BLC_;          // scratch: mem_combined lives in out[BLC : 2*BLC)

    dim3 blk(256);

    // 1. query = x @ Wq  -> out_lo (scratch)
    gemm_kernel<<<dim3(C_ / TILE, (B_ * L_) / TILE), blk, 0, stream>>>(
        x, Wq, qbuf, B_ * L_, C_, C_, nullptr, nullptr);
    // 2. keys = mem @ Wk, values = mem @ Wv
    gemm_kernel<<<dim3(C_ / TILE, 1280 / TILE), blk, 0, stream>>>(
        mem, Wk, keys, 1280, C_, C_, nullptr, nullptr);
    gemm_kernel<<<dim3(C_ / TILE, 1280 / TILE), blk, 0, stream>>>(
        mem, Wv, vals, 1280, C_, C_, nullptr, nullptr);
    // 3. segmented attention -> mem_combined in out_hi (scratch)
    attn_kernel<<<dim3(47, B_), blk, 0, stream>>>(qbuf, keys, vals, lt, mc);
    // 4. hidden projections (rank 64)
    gemm_kernel<<<dim3(1, (B_ * L_) / TILE), blk, 0, stream>>>(
        mc, wk1, hk, B_ * L_, 64, C_, bk1, nullptr);
    gemm_kernel<<<dim3(1, (B_ * L_) / TILE), blk, 0, stream>>>(
        mc, wv1, hv, B_ * L_, 64, C_, bv1, nullptr);
    // 5. outputs: mem_k -> out_lo (overwrites query), mem_v -> out_hi (overwrites mem_combined)
    gemm_kernel<<<dim3(C_ / TILE, (B_ * L_) / TILE), blk, 0, stream>>>(
        hk, wk2, out, B_ * L_, C_, 64, bk2, gk);
    gemm_kernel<<<dim3(C_ / TILE, (B_ * L_) / TILE), blk, 0, stream>>>(
        hv, wv2, out + BLC_, B_ * L_, C_, 64, bv2, gv);
    // 6. trailing two scalar zeros
    tail_kernel<<<1, 1, 0, stream>>>(out + 2 * BLC_);
}